// Round 4
// baseline (208.428 us; speedup 1.0000x reference)
//
#include <hip/hip_runtime.h>
#include <hip/hip_bf16.h>

#define B_  32
#define S_  1024
#define E_  768
#define HD_ 64
#define M_  (B_*S_)   // 32768 rows of x

typedef __attribute__((ext_vector_type(8))) short short8;   // 8 bf16 (4 VGPR)
typedef __attribute__((ext_vector_type(4))) float float4v;  // MFMA acc

// fp32 -> bf16 round-to-nearest-even
__device__ __forceinline__ unsigned short f2bf(float x) {
    union { float f; unsigned u; } c; c.f = x;
    unsigned r = (c.u + 0x7FFFu + ((c.u >> 16) & 1u)) >> 16;
    return (unsigned short)r;
}

// async global->LDS, 16B per lane; LDS dest = wave-uniform tile base.
__device__ __forceinline__ void gld_lds16(const void* g, void* l) {
    __builtin_amdgcn_global_load_lds(
        (const __attribute__((address_space(1))) unsigned int*)g,
        (__attribute__((address_space(3))) unsigned int*)l,
        16, 0, 0);
}

// ---------------------------------------------------------------------------
// RoPE tables (blocks 0..127) + dtype sniffer (block 128). (unchanged)
// ---------------------------------------------------------------------------
__global__ __launch_bounds__(256) void setup_kernel(const unsigned int* __restrict__ xw,
                                                    unsigned int* __restrict__ flag,
                                                    float* __restrict__ cs_t,
                                                    float* __restrict__ sn_t) {
    if (blockIdx.x == 128) {   // dtype sniffer (verified rounds 2-5)
        __shared__ int cnt;
        if (threadIdx.x == 0) cnt = 0;
        __syncthreads();
        unsigned int w = xw[(size_t)threadIdx.x * 33331];
        unsigned int e = (w >> 8) & 0x7F;
        int hit = (e >= 0x3B && e <= 0x40) ? 1 : 0;
        atomicAdd(&cnt, hit);
        __syncthreads();
        if (threadIdx.x == 0) *flag = (cnt > 128) ? 1u : 0u;
        return;
    }
    int idx = blockIdx.x * 256 + threadIdx.x;   // 0 .. 32767
    int pos = idx >> 5;
    int ii  = idx & 31;
    float theta = exp2f(-(float)ii * 0.8304820237218406f);  // log2(10000)/16
    float fr = (float)pos * theta;
    float sn, cs;
    sincosf(fr, &sn, &cs);
    cs_t[idx] = cs;
    sn_t[idx] = sn;
}

// ---------------------------------------------------------------------------
// W pre-pack: fragment-tile order Wp[ct(12)][c(12)][ks(2)][lane(64)][8 bf16].
// (unchanged from round 3)
// ---------------------------------------------------------------------------
__global__ __launch_bounds__(256) void wpack_kernel(
    const void* __restrict__ Wq_, const void* __restrict__ Wk_,
    const void* __restrict__ Wv_, const unsigned int* __restrict__ flag,
    unsigned short* __restrict__ wp)
{
    const bool isb = (*flag != 0);
    int gid  = blockIdx.x * 256 + threadIdx.x;   // 0..18431
    int lane = gid & 63;
    int tIdx = gid >> 6;                          // 0..287
    int ct   = tIdx / 24;
    int rem  = tIdx - ct * 24;
    int c    = rem >> 1, ks = rem & 1;
    int quad = lane >> 4, l15 = lane & 15;
    const void* wsel = (ct < 4) ? Wq_ : (ct < 8 ? Wk_ : Wv_);
    int row = (ct & 3) * 16 + l15;
    int col = c * 64 + ks * 32 + quad * 8;
    uint4 w;
    if (isb) {
        w = *(const uint4*)((const unsigned short*)wsel + (size_t)row * E_ + col);
    } else {
        const float* f = (const float*)wsel + (size_t)row * E_ + col;
        float4 a = *(const float4*)f, bq = *(const float4*)(f + 4);
        w.x = f2bf(a.x)  | ((unsigned)f2bf(a.y)  << 16);
        w.y = f2bf(a.z)  | ((unsigned)f2bf(a.w)  << 16);
        w.z = f2bf(bq.x) | ((unsigned)f2bf(bq.y) << 16);
        w.w = f2bf(bq.z) | ((unsigned)f2bf(bq.w) << 16);
    }
    *(uint4*)(wp + (size_t)gid * 8) = w;
}

// ---------------------------------------------------------------------------
// QKV projection + RoPE, MFMA 16x16x32 bf16.
// ROUND-4 CHANGE: T3+T4 counted-vmcnt ring pipeline (was: whole-A prologue
// drain + per-chunk __syncthreads vmcnt(0) drain -> 85% stall cycles).
// - 4-slot LDS ring, slot = chunk & 3, per slot: A 8KB + B 24KB (128 KB).
// - Per chunk each wave issues EXACTLY 4 gld_lds (1 A + 3 B) -> uniform
//   vmcnt counting. Prologue stages chunks 0..2 (12/wave outstanding).
// - Loop c: s_waitcnt vmcnt(8) [chunk c landed, c+1/c+2 in flight] ->
//   raw s_barrier -> stage(c+3) [dead-slot dummy past 11] -> compute c.
//   vmcnt NEVER drains to 0 in the main loop (T4).
// - A chunk layout: [64 rows][128B], 16B slot s holds global slot s^(row&7)
//   (both-sides swizzle: source-permuted within 128B windows -> each A
//   gld_lds stays 8 x 128B segments; ds_read uses the same XOR).
// - B from wpack'd wp: fully linear tiles.
// Race analysis: stage(c+3) writes slot (c-1)&3; every wave passed the
// iter-c barrier only after finishing compute c-1 (lgkm waits precede its
// MFMAs). Visibility: per-wave vmcnt(8) before barrier => all waves' chunk-c
// loads complete before any wave computes c.
// Block 512 thr (8 waves): wave h=w>>2 (2 mt), cw=w&3 (3 ct). Grid 512.
// ---------------------------------------------------------------------------
__global__ __launch_bounds__(512, 1) void qkv_mfma_kernel(
    const void* __restrict__ x_, const unsigned short* __restrict__ wp,
    const unsigned int* __restrict__ flag,
    const float* __restrict__ cs_t, const float* __restrict__ sn_t,
    unsigned short* __restrict__ rq_p, unsigned short* __restrict__ rk_p,
    unsigned short* __restrict__ vt_p)
{
    __shared__ __align__(16) char lds[4][32768];   // ring: A [0,8K) + B [8K,32K)

    const bool isb = (*flag != 0);
    const int t    = threadIdx.x;
    const int lane = t & 63;
    const int wave = t >> 6;        // 0..7
    const int quad = lane >> 4;
    const int l15  = lane & 15;
    const int row0 = blockIdx.x * 64;
    const int h    = wave >> 2;     // row half: mt tiles {h*2, h*2+1}
    const int cw   = wave & 3;      // col group: ct = cw*3 + nt

    // ---- A stage descriptor: wave w covers rows w*8..w*8+7 of the chunk.
    // lane j: global row w*8+(j>>3), within-chunk col elems ((j&7)^(j>>3))*8
    // -> LDS linear dest (row j>>3, stored slot j&7). 8 x 128B segments.
    const unsigned aRow  = (unsigned)(wave * 8 + (lane >> 3));
    const unsigned eoA   = aRow * 768u + (unsigned)(((lane & 7) ^ (lane >> 3)) * 8);

    // ---- B stage descriptors: 3 linear tiles per wave per chunk ----
    unsigned eoB[3]; int tidB[3];
    #pragma unroll
    for (int i = 0; i < 3; ++i) {
        int idx = wave * 3 + i;            // 0..23: ct = idx>>1, ks = idx&1
        int ct = idx >> 1, ks = idx & 1;
        eoB[i]  = (unsigned)(ct * 12288 + ks * 512 + lane * 8);  // + c*1024 elems
        tidB[i] = idx;
    }

    // ---- A fragment read byte-addrs within slot ----
    unsigned aA[2][2];
    #pragma unroll
    for (int mtl = 0; mtl < 2; ++mtl) {
        unsigned rl = (unsigned)((h * 2 + mtl) * 16 + l15);
        #pragma unroll
        for (int ks = 0; ks < 2; ++ks)
            aA[mtl][ks] = rl * 128u + ((((unsigned)ks << 2) | (unsigned)quad) ^ (rl & 7u)) * 16u;
    }

    float4v acc[3][2];
    #pragma unroll
    for (int nt = 0; nt < 3; ++nt)
        #pragma unroll
        for (int mtl = 0; mtl < 2; ++mtl)
            #pragma unroll
            for (int r = 0; r < 4; ++r) acc[nt][mtl][r] = 0.f;

    const unsigned short* xb16 = (const unsigned short*)x_ + (size_t)row0 * E_;
    const float*          xb32 = (const float*)x_ + (size_t)row0 * E_;

    // bf16 stage: 4 gld_lds per wave, FIFO order (A then B x3)
    auto stage_b = [&](int c) {
        int tc = (c < 11) ? c : 11;        // dummy re-stage into dead slot past end
        char* dst = lds[c & 3];
        gld_lds16(xb16 + eoA + tc * 64, dst + wave * 1024);
        #pragma unroll
        for (int i = 0; i < 3; ++i)
            gld_lds16(wp + (size_t)eoB[i] + (unsigned)tc * 1024u,
                      dst + 8192 + tidB[i] * 1024);
    };
    // f32 stage: A via reg-convert ds_write; B still gld_lds (wp is bf16)
    auto stage_f = [&](int c) {
        int tc = (c < 11) ? c : 11;
        char* dst = lds[c & 3];
        {
            const float* f = xb32 + eoA + tc * 64;
            float4 a = *(const float4*)f, bq = *(const float4*)(f + 4);
            uint4 w;
            w.x = f2bf(a.x)  | ((unsigned)f2bf(a.y)  << 16);
            w.y = f2bf(a.z)  | ((unsigned)f2bf(a.w)  << 16);
            w.z = f2bf(bq.x) | ((unsigned)f2bf(bq.y) << 16);
            w.w = f2bf(bq.z) | ((unsigned)f2bf(bq.w) << 16);
            *(uint4*)(dst + wave * 1024 + lane * 16) = w;
        }
        #pragma unroll
        for (int i = 0; i < 3; ++i)
            gld_lds16(wp + (size_t)eoB[i] + (unsigned)tc * 1024u,
                      dst + 8192 + tidB[i] * 1024);
    };

    #define QKV_COMPUTE(sb)                                                          \
        _Pragma("unroll")                                                            \
        for (int ks = 0; ks < 2; ++ks) {                                             \
            short8 af[2];                                                            \
            af[0] = *(const short8*)((sb) + aA[0][ks]);                              \
            af[1] = *(const short8*)((sb) + aA[1][ks]);                              \
            _Pragma("unroll")                                                        \
            for (int nt = 0; nt < 3; ++nt) {                                         \
                int ct = cw * 3 + nt;                                                \
                short8 bf = *(const short8*)((sb) + 8192 + (ct * 2 + ks) * 1024      \
                                             + lane * 16);                           \
                acc[nt][0] = __builtin_amdgcn_mfma_f32_16x16x32_bf16(                \
                    af[0], bf, acc[nt][0], 0, 0, 0);                                 \
                acc[nt][1] = __builtin_amdgcn_mfma_f32_16x16x32_bf16(                \
                    af[1], bf, acc[nt][1], 0, 0, 0);                                 \
            }                                                                        \
        }

    if (isb) {
        stage_b(0); stage_b(1); stage_b(2);
        for (int c = 0; c < 12; ++c) {
            asm volatile("s_waitcnt vmcnt(8)" ::: "memory");
            __builtin_amdgcn_s_barrier();
            stage_b(c + 3);
            const char* sb = lds[c & 3];
            QKV_COMPUTE(sb)
        }
    } else {
        // correctness fallback: same ring, full drains
        stage_f(0); stage_f(1); stage_f(2);
        for (int c = 0; c < 12; ++c) {
            __syncthreads();
            stage_f(c + 3);
            const char* sb = lds[c & 3];
            QKV_COMPUTE(sb)
        }
    }
    #undef QKV_COMPUTE

    // ---- Epilogue (unchanged r3): C col=l15, row=quad*4+r. RoPE q/k; v transposed.
    const int b      = row0 >> 10;
    const int s_in_b = row0 & (S_ - 1);
    #pragma unroll
    for (int nt = 0; nt < 3; ++nt) {
        int ct = cw * 3 + nt;
        int region = ct >> 2;          // 0=q, 1=k, 2=v (wave-uniform)
        int d = (ct & 3) * 16 + l15;
        if (region < 2) {
            unsigned short* dst = (region == 0) ? rq_p : rk_p;
            int ii = d >> 1;
            int ksq = d >> 5, quadq = (d >> 3) & 3, e = d & 7;
            #pragma unroll
            for (int mtl = 0; mtl < 2; ++mtl) {
                #pragma unroll
                for (int r = 0; r < 4; ++r) {
                    int row = row0 + (h * 2 + mtl) * 16 + quad * 4 + r;
                    int pos = row & (S_ - 1);
                    float cs = cs_t[pos * 32 + ii];
                    float sn = sn_t[pos * 32 + ii];
                    float val = acc[nt][mtl][r];
                    float partner = __shfl_xor(val, 1);   // pair col d^1 = lane^1
                    float res = (d & 1) ? fmaf(val, cs,  partner * sn)
                                        : fmaf(val, cs, -partner * sn);
                    int kt = pos >> 6, ntq = (pos >> 4) & 3, l15q = pos & 15;
                    size_t idx = ((((size_t)(b * 16 + kt) * 4 + ntq) * 2 + ksq) * 64
                                  + quadq * 16 + l15q) * 8 + e;
                    dst[idx] = f2bf(res);
                }
            }
        } else {
            int ntv = ct & 3;          // d = ntv*16 + l15
            #pragma unroll
            for (int mtl = 0; mtl < 2; ++mtl) {
                int sb2 = s_in_b + (h * 2 + mtl) * 16 + quad * 4;
                int kt = sb2 >> 6, ksv = (sb2 >> 5) & 1, quadv = (sb2 >> 3) & 3, e0 = sb2 & 7;
                ushort4 pk;
                pk.x = f2bf(acc[nt][mtl][0]);
                pk.y = f2bf(acc[nt][mtl][1]);
                pk.z = f2bf(acc[nt][mtl][2]);
                pk.w = f2bf(acc[nt][mtl][3]);
                size_t idx = ((((size_t)(b * 16 + kt) * 4 + ntv) * 2 + ksv) * 64
                              + quadv * 16 + l15) * 8 + e0;
                *(ushort4*)(vt_p + idx) = pk;
            }
        }
    }
}

// ---------------------------------------------------------------------------
// Flash attention — unchanged from round 3 (packed linear staging).
// ---------------------------------------------------------------------------
__global__ __launch_bounds__(256, 2) void attn_mfma_kernel(
    const unsigned short* __restrict__ rq_p, const unsigned short* __restrict__ rk_p,
    const unsigned short* __restrict__ vt_p, const unsigned int* __restrict__ flag,
    void* __restrict__ out)
{
    __shared__ __align__(16) unsigned short kv[2][32 * 512];   // 2 x 32 KB
    __shared__ unsigned short plds[4][16][72];                 // per-wave P buffer

    const bool isb = (*flag != 0);
    const int t    = threadIdx.x;
    const int lane = t & 63;
    const int wave = t >> 6;
    const int quad = lane >> 4;
    const int l15  = lane & 15;
    const int qt   = blockIdx.x;
    const int b    = blockIdx.y;
    const int q0   = qt * 64 + wave * 16;
    const float scale = 0.03608439182435161f;   // 768^-0.5

    // Q A-frags from packed tile (b, kt=qt, nt=wave)
    const unsigned short* qb = rq_p + ((size_t)((b * 16 + qt) * 4 + wave) * 2) * 512;
    short8 qf0 = *(const short8*)(qb + lane * 8);
    short8 qf1 = *(const short8*)(qb + 512 + lane * 8);

    // staging descriptors: this wave's 8 tiles, all linear
    const unsigned short* sbase[8];
    unsigned eo[8];
    int      slotv[8], tidv[8];
    #pragma unroll
    for (int i = 0; i < 8; ++i) {
        int tid = wave * 8 + i;
        tidv[i] = tid;
        int isV  = tid >> 4;             // 0=K, 1=V
        int rem  = tid & 15;
        int slot = rem >> 3;
        int wi   = rem & 7;
        int nt   = wi >> 1, ks = wi & 1;
        slotv[i] = slot;
        sbase[i] = isV ? vt_p : rk_p;
        eo[i]    = (unsigned)(((b * 64 + nt) * 2 + ks) * 512 + lane * 8);  // kt=0 base
    }

    float4v o[4];
    float m_[4], l_[4];
    #pragma unroll
    for (int nt = 0; nt < 4; ++nt)
        #pragma unroll
        for (int r = 0; r < 4; ++r) o[nt][r] = 0.f;
    #pragma unroll
    for (int r = 0; r < 4; ++r) { m_[r] = -1e30f; l_[r] = 0.f; }

    const int nIter = (qt + 2) >> 1;

    auto stage = [&](int it, int bsel) {
        int ta  = 2 * it;
        int tb  = min(ta + 1, qt);
        #pragma unroll
        for (int i = 0; i < 8; ++i) {
            int kt = slotv[i] ? tb : ta;
            gld_lds16(sbase[i] + eo[i] + (size_t)kt * 4096,   // kt stride = 4*2*512
                      &kv[bsel][(size_t)tidv[i] * 512]);
        }
    };

    stage(0, 0);
    int buf = 0;
    for (int i = 0; i < nIter; ++i) {
        __syncthreads();
        if (i + 1 < nIter) stage(i + 1, buf ^ 1);
        const unsigned short* kb = kv[buf];

        // ---- S = Q K^T for both slots ----
        float sc[2][4][4];
        #pragma unroll
        for (int slot = 0; slot < 2; ++slot) {
            #pragma unroll
            for (int nt = 0; nt < 4; ++nt) {
                float4v s;
                #pragma unroll
                for (int r = 0; r < 4; ++r) s[r] = 0.f;
                short8 kf0 = *(const short8*)(kb + (size_t)(slot * 8 + nt * 2 + 0) * 512 + lane * 8);
                short8 kf1 = *(const short8*)(kb + (size_t)(slot * 8 + nt * 2 + 1) * 512 + lane * 8);
                s = __builtin_amdgcn_mfma_f32_16x16x32_bf16(qf0, kf0, s, 0, 0, 0);
                s = __builtin_amdgcn_mfma_f32_16x16x32_bf16(qf1, kf1, s, 0, 0, 0);
                #pragma unroll
                for (int r = 0; r < 4; ++r) sc[slot][nt][r] = s[r] * scale;
            }
        }

        // ---- causal mask (wave-uniform trigger near diagonal) ----
        if (2 * i + 1 >= qt) {
            #pragma unroll
            for (int slot = 0; slot < 2; ++slot) {
                int ktl = 2 * i + slot;     // LOGICAL tile (dup tail -> all masked)
                #pragma unroll
                for (int nt = 0; nt < 4; ++nt) {
                    int kg = ktl * 64 + nt * 16 + l15;
                    #pragma unroll
                    for (int r = 0; r < 4; ++r) {
                        int qg = q0 + quad * 4 + r;
                        if (kg > qg) sc[slot][nt][r] = -1e30f;
                    }
                }
            }
        }

        // ---- online softmax over 128 keys (16-lane reduce) ----
        float mx[4];
        #pragma unroll
        for (int r = 0; r < 4; ++r) {
            float a0 = fmaxf(fmaxf(sc[0][0][r], sc[0][1][r]), fmaxf(sc[0][2][r], sc[0][3][r]));
            float a1 = fmaxf(fmaxf(sc[1][0][r], sc[1][1][r]), fmaxf(sc[1][2][r], sc[1][3][r]));
            mx[r] = fmaxf(a0, a1);
        }
        #pragma unroll
        for (int st = 1; st < 16; st <<= 1)
            #pragma unroll
            for (int r = 0; r < 4; ++r)
                mx[r] = fmaxf(mx[r], __shfl_xor(mx[r], st));

        float al[4];
        #pragma unroll
        for (int r = 0; r < 4; ++r) {
            float mn = fmaxf(m_[r], mx[r]);
            al[r] = __expf(m_[r] - mn);
            m_[r] = mn;
        }

        float sm[4] = {0.f, 0.f, 0.f, 0.f};
        #pragma unroll
        for (int slot = 0; slot < 2; ++slot)
            #pragma unroll
            for (int nt = 0; nt < 4; ++nt)
                #pragma unroll
                for (int r = 0; r < 4; ++r) {
                    float p = __expf(sc[slot][nt][r] - m_[r]);
                    sc[slot][nt][r] = p;
                    sm[r] += p;
                }
        #pragma unroll
        for (int st = 1; st < 16; st <<= 1)
            #pragma unroll
            for (int r = 0; r < 4; ++r)
                sm[r] += __shfl_xor(sm[r], st);
        #pragma unroll
        for (int r = 0; r < 4; ++r) l_[r] = l_[r] * al[r] + sm[r];

        #pragma unroll
        for (int nt = 0; nt < 4; ++nt)
            #pragma unroll
            for (int r = 0; r < 4; ++r) o[nt][r] *= al[r];

        // ---- per slot: P -> LDS -> A-frag; O += P V ----
        #pragma unroll
        for (int slot = 0; slot < 2; ++slot) {
            #pragma unroll
            for (int nt = 0; nt < 4; ++nt)
                #pragma unroll
                for (int r = 0; r < 4; ++r)
                    plds[wave][quad * 4 + r][nt * 16 + l15] = f2bf(sc[slot][nt][r]);
            short8 pf0 = *(const short8*)&plds[wave][l15][quad * 8];
            short8 pf1 = *(const short8*)&plds[wave][l15][32 + quad * 8];
            #pragma unroll
            for (int nt = 0; nt < 4; ++nt) {
                short8 vf0 = *(const short8*)(kb + (size_t)(16 + slot * 8 + nt * 2 + 0) * 512 + lane * 8);
                short8 vf1 = *(const short8*)(kb + (size_t)(16 + slot * 8 + nt * 2 + 1) * 512 + lane * 8);
                o[nt] = __builtin_amdgcn_mfma_f32_16x16x32_bf16(pf0, vf0, o[nt], 0, 0, 0);
                o[nt] = __builtin_amdgcn_mfma_f32_16x16x32_bf16(pf1, vf1, o[nt], 0, 0, 0);
            }
        }
        buf ^= 1;
    }

    // ---- epilogue: normalize, store per dtype ----
    float inv[4];
    #pragma unroll
    for (int r = 0; r < 4; ++r) inv[r] = 1.0f / l_[r];
    if (isb) {
        unsigned short* op = (unsigned short*)out;
        #pragma unroll
        for (int nt = 0; nt < 4; ++nt)
            #pragma unroll
            for (int r = 0; r < 4; ++r) {
                size_t row = (size_t)b * S_ + q0 + quad * 4 + r;
                op[row * HD_ + nt * 16 + l15] = f2bf(o[nt][r] * inv[r]);
            }
    } else {
        float* op = (float*)out;
        #pragma unroll
        for (int nt = 0; nt < 4; ++nt)
            #pragma unroll
            for (int r = 0; r < 4; ++r) {
                size_t row = (size_t)b * S_ + q0 + quad * 4 + r;
                op[row * HD_ + nt * 16 + l15] = o[nt][r] * inv[r];
            }
    }
}

// ---------------------------------------------------------------------------
extern "C" void kernel_launch(void* const* d_in, const int* in_sizes, int n_in,
                              void* d_out, int out_size, void* d_ws, size_t ws_size,
                              hipStream_t stream) {
    const void* x  = d_in[0];
    const void* Wq = d_in[1];
    const void* Wk = d_in[2];
    const void* Wv = d_in[3];

    // ws layout (~12.9 MB)
    unsigned int* flag = (unsigned int*)d_ws;
    float* cs_t = (float*)d_ws + 64;
    float* sn_t = cs_t + (size_t)S_ * 32;
    unsigned short* wp   = (unsigned short*)(sn_t + (size_t)S_ * 32);  // 288 tiles
    unsigned short* rq_p = wp + (size_t)288 * 512;
    unsigned short* rk_p = rq_p + (size_t)M_ * HD_;
    unsigned short* vt_p = rk_p + (size_t)M_ * HD_;

    hipLaunchKernelGGL(setup_kernel, dim3(129), dim3(256), 0, stream,
                       (const unsigned int*)x, flag, cs_t, sn_t);
    hipLaunchKernelGGL(wpack_kernel, dim3(72), dim3(256), 0, stream,
                       Wq, Wk, Wv, flag, wp);
    hipLaunchKernelGGL(qkv_mfma_kernel, dim3(M_ / 64), dim3(512), 0, stream,
                       x, wp, flag, cs_t, sn_t, rq_p, rk_p, vt_p);
    hipLaunchKernelGGL(attn_mfma_kernel, dim3(S_ / 64, B_), dim3(256), 0, stream,
                       rq_p, rk_p, vt_p, flag, d_out);
}

// Round 5
// 194.766 us; speedup vs baseline: 1.0701x; 1.0701x over previous
//
#include <hip/hip_runtime.h>
#include <hip/hip_bf16.h>

#define B_  32
#define S_  1024
#define E_  768
#define HD_ 64
#define M_  (B_*S_)   // 32768 rows of x

typedef __attribute__((ext_vector_type(8))) short short8;   // 8 bf16 (4 VGPR)
typedef __attribute__((ext_vector_type(4))) float float4v;  // MFMA acc

// fp32 -> bf16 round-to-nearest-even
__device__ __forceinline__ unsigned short f2bf(float x) {
    union { float f; unsigned u; } c; c.f = x;
    unsigned r = (c.u + 0x7FFFu + ((c.u >> 16) & 1u)) >> 16;
    return (unsigned short)r;
}

// async global->LDS, 16B per lane; LDS dest = wave-uniform tile base.
__device__ __forceinline__ void gld_lds16(const void* g, void* l) {
    __builtin_amdgcn_global_load_lds(
        (const __attribute__((address_space(1))) unsigned int*)g,
        (__attribute__((address_space(3))) unsigned int*)l,
        16, 0, 0);
}

// ---------------------------------------------------------------------------
// Fused setup: RoPE tables (blocks 0..127), dtype sniffer -> flag (block 128),
// W pre-pack (blocks 129..200; inline per-block sniff avoids flag race).
// Wp[ct(12)][c(12)][ks(2)][lane(64)][8 bf16] fragment order (r3, verified).
// ---------------------------------------------------------------------------
__global__ __launch_bounds__(256) void setup_kernel(
    const unsigned int* __restrict__ xw,
    const void* __restrict__ Wq_, const void* __restrict__ Wk_,
    const void* __restrict__ Wv_,
    unsigned int* __restrict__ flag,
    float* __restrict__ cs_t, float* __restrict__ sn_t,
    unsigned short* __restrict__ wp)
{
    const int bx = blockIdx.x;
    if (bx < 128) {                     // RoPE tables
        int idx = bx * 256 + threadIdx.x;   // 0 .. 32767
        int pos = idx >> 5;
        int ii  = idx & 31;
        float theta = exp2f(-(float)ii * 0.8304820237218406f);  // log2(10000)/16
        float fr = (float)pos * theta;
        float sn, cs;
        sincosf(fr, &sn, &cs);
        cs_t[idx] = cs;
        sn_t[idx] = sn;
        return;
    }
    // blocks 128..200: sniff dtype (verified rounds 2-5 logic)
    __shared__ int cnt;
    if (threadIdx.x == 0) cnt = 0;
    __syncthreads();
    unsigned int w0 = xw[(size_t)threadIdx.x * 33331];
    unsigned int e0 = (w0 >> 8) & 0x7F;
    int hit = (e0 >= 0x3B && e0 <= 0x40) ? 1 : 0;
    atomicAdd(&cnt, hit);
    __syncthreads();
    const bool isb = (cnt > 128);
    if (bx == 128) {
        if (threadIdx.x == 0) *flag = isb ? 1u : 0u;
        return;
    }
    // wpack body (blocks 129..200 -> gid 0..18431)
    int gid  = (bx - 129) * 256 + threadIdx.x;
    int lane = gid & 63;
    int tIdx = gid >> 6;                          // 0..287
    int ct   = tIdx / 24;
    int rem  = tIdx - ct * 24;
    int c    = rem >> 1, ks = rem & 1;
    int quad = lane >> 4, l15 = lane & 15;
    const void* wsel = (ct < 4) ? Wq_ : (ct < 8 ? Wk_ : Wv_);
    int row = (ct & 3) * 16 + l15;
    int col = c * 64 + ks * 32 + quad * 8;
    uint4 w;
    if (isb) {
        w = *(const uint4*)((const unsigned short*)wsel + (size_t)row * E_ + col);
    } else {
        const float* f = (const float*)wsel + (size_t)row * E_ + col;
        float4 a = *(const float4*)f, bq = *(const float4*)(f + 4);
        w.x = f2bf(a.x)  | ((unsigned)f2bf(a.y)  << 16);
        w.y = f2bf(a.z)  | ((unsigned)f2bf(a.w)  << 16);
        w.z = f2bf(bq.x) | ((unsigned)f2bf(bq.y) << 16);
        w.w = f2bf(bq.z) | ((unsigned)f2bf(bq.w) << 16);
    }
    *(uint4*)(wp + (size_t)gid * 8) = w;
}

// ---------------------------------------------------------------------------
// QKV projection + RoPE, MFMA 16x16x32 bf16.
// ROUND-5 CHANGE: minimize LDS-DMA instruction count. Cross-round evidence:
// time tracks gld_lds instr count (~190-237 cyc/instr/CU) regardless of
// occupancy (r2), barriers (r4), contiguity (r3, mild). So:
// - B: NO LDS at all. wp is fragment-ordered -> each wave loads its 6 B
//   frags per chunk straight to registers (coalesced dwordx4, L2-hot,
//   double-buffered regs, deep pipelined queue).
// - A: still via LDS (cross-wave row sharing), ring-3 x 8KB = 24 KB,
//   exactly 1 gld_lds per wave per chunk (14/block vs r4's 384/block).
// - Counted wait: per iter issue [B(c+1) x6, A(c+2) x1] (order pinned with
//   sched_barrier); top of iter: vmcnt(1) forces B(c)+A(c) complete, leaves
//   A(c+1) in flight. Uniform 7 instrs/iter via clamped dummies.
// - A slot layout (r4, verified): [64 rows][128B], 16B slot s holds global
//   slot s^(row&7); read addr slot ((ks<<2)|quad)^(row&7). 2-way banks.
// Block 512 thr (8 waves): wave h=w>>2 (2 mt), cw=w&3 (3 ct). Grid 512,
// 24 KB LDS + <=128 VGPR -> 2 blocks/CU.
// ---------------------------------------------------------------------------
__global__ __launch_bounds__(512, 4) void qkv_mfma_kernel(
    const void* __restrict__ x_, const unsigned short* __restrict__ wp,
    const unsigned int* __restrict__ flag,
    const float* __restrict__ cs_t, const float* __restrict__ sn_t,
    unsigned short* __restrict__ rq_p, unsigned short* __restrict__ rk_p,
    unsigned short* __restrict__ vt_p)
{
    __shared__ __align__(16) char alds[3][8192];   // A ring

    const bool isb = (*flag != 0);
    const int t    = threadIdx.x;
    const int lane = t & 63;
    const int wave = t >> 6;        // 0..7
    const int quad = lane >> 4;
    const int l15  = lane & 15;
    const int row0 = blockIdx.x * 64;
    const int h    = wave >> 2;     // row half: mt tiles {h*2, h*2+1}
    const int cw   = wave & 3;      // col group: ct = cw*3 + nt

    // A stage descriptor: 1 instr/wave/chunk; wave covers rows wave*8..+7.
    // lane j: row wave*8+(j>>3), col elems ((j&7)^(j>>3))*8 (source-swizzled).
    const unsigned aRow = (unsigned)(wave * 8 + (lane >> 3));
    const unsigned eoA  = aRow * 768u + (unsigned)(((lane & 7) ^ (lane >> 3)) * 8);

    // A fragment read byte-addrs within a slot
    unsigned aA[2][2];
    #pragma unroll
    for (int mtl = 0; mtl < 2; ++mtl) {
        unsigned rl = (unsigned)((h * 2 + mtl) * 16 + l15);
        #pragma unroll
        for (int ks = 0; ks < 2; ++ks)
            aA[mtl][ks] = rl * 128u + ((((unsigned)ks << 2) | (unsigned)quad) ^ (rl & 7u)) * 16u;
    }

    // B fragment bases (chunk stride = 1024 elems)
    const unsigned short* wbase[3][2];
    #pragma unroll
    for (int nt = 0; nt < 3; ++nt) {
        int ct = cw * 3 + nt;
        #pragma unroll
        for (int ks = 0; ks < 2; ++ks)
            wbase[nt][ks] = wp + ((size_t)(ct * 24 + ks)) * 512 + lane * 8;
    }

    float4v acc[3][2];
    #pragma unroll
    for (int nt = 0; nt < 3; ++nt)
        #pragma unroll
        for (int mtl = 0; mtl < 2; ++mtl)
            #pragma unroll
            for (int r = 0; r < 4; ++r) acc[nt][mtl][r] = 0.f;

    short8 breg[2][3][2];   // double-buffered B frags (static idx under unroll)

    const unsigned short* xb16 = (const unsigned short*)x_ + (size_t)row0 * E_;
    const float*          xb32 = (const float*)x_ + (size_t)row0 * E_;

    #define LOADB(cc, sel)                                                       \
        {   int tc_ = (cc) < 11 ? (cc) : 11;                                     \
            _Pragma("unroll")                                                    \
            for (int nt_ = 0; nt_ < 3; ++nt_)                                    \
                _Pragma("unroll")                                                \
                for (int ks_ = 0; ks_ < 2; ++ks_)                                \
                    breg[sel][nt_][ks_] =                                        \
                        *(const short8*)(wbase[nt_][ks_] + tc_ * 1024);          \
        }

    #define COMPUTE(cc, sel)                                                     \
        {   const char* sb_ = alds[(cc) % 3];                                    \
            _Pragma("unroll")                                                    \
            for (int ks_ = 0; ks_ < 2; ++ks_) {                                  \
                short8 af0 = *(const short8*)(sb_ + aA[0][ks_]);                 \
                short8 af1 = *(const short8*)(sb_ + aA[1][ks_]);                 \
                _Pragma("unroll")                                                \
                for (int nt_ = 0; nt_ < 3; ++nt_) {                              \
                    acc[nt_][0] = __builtin_amdgcn_mfma_f32_16x16x32_bf16(       \
                        af0, breg[sel][nt_][ks_], acc[nt_][0], 0, 0, 0);         \
                    acc[nt_][1] = __builtin_amdgcn_mfma_f32_16x16x32_bf16(       \
                        af1, breg[sel][nt_][ks_], acc[nt_][1], 0, 0, 0);         \
                }                                                                \
            }                                                                    \
        }

    if (isb) {
        // prologue: [B(0) x6, A(0), A(1)] -> vmcnt(1) at iter 0 forces B0,A0.
        LOADB(0, 0);
        __builtin_amdgcn_sched_barrier(0);
        gld_lds16(xb16 + eoA,      alds[0] + wave * 1024);
        gld_lds16(xb16 + eoA + 64, alds[1] + wave * 1024);
        __builtin_amdgcn_sched_barrier(0);
        #pragma unroll
        for (int c = 0; c < 12; ++c) {
            asm volatile("s_waitcnt vmcnt(1)" ::: "memory");
            __builtin_amdgcn_s_barrier();
            // issue order pinned: B(c+1) x6 then A(c+2) x1
            LOADB(c + 1, (c + 1) & 1);
            __builtin_amdgcn_sched_barrier(0);
            {
                int tc = (c + 2) < 11 ? (c + 2) : 11;
                gld_lds16(xb16 + eoA + tc * 64, alds[(c + 2) % 3] + wave * 1024);
            }
            __builtin_amdgcn_sched_barrier(0);
            COMPUTE(c, c & 1);
        }
    } else {
        // f32 correctness path: A via reg-convert ds_write, full syncs.
        auto stageA_f = [&](int c) {
            const float* f = xb32 + eoA + c * 64;
            float4 a = *(const float4*)f, bq = *(const float4*)(f + 4);
            uint4 w;
            w.x = f2bf(a.x)  | ((unsigned)f2bf(a.y)  << 16);
            w.y = f2bf(a.z)  | ((unsigned)f2bf(a.w)  << 16);
            w.z = f2bf(bq.x) | ((unsigned)f2bf(bq.y) << 16);
            w.w = f2bf(bq.z) | ((unsigned)f2bf(bq.w) << 16);
            *(uint4*)(alds[c % 3] + wave * 1024 + (size_t)lane * 16) = w;
        };
        stageA_f(0); stageA_f(1);
        LOADB(0, 0);
        __syncthreads();
        #pragma unroll
        for (int c = 0; c < 12; ++c) {
            if (c + 2 < 12) stageA_f(c + 2);
            LOADB(c + 1, (c + 1) & 1);
            COMPUTE(c, c & 1);
            __syncthreads();
        }
    }
    #undef LOADB
    #undef COMPUTE

    // ---- Epilogue (unchanged r3/r4, verified): C col=l15, row=quad*4+r.
    const int b      = row0 >> 10;
    const int s_in_b = row0 & (S_ - 1);
    #pragma unroll
    for (int nt = 0; nt < 3; ++nt) {
        int ct = cw * 3 + nt;
        int region = ct >> 2;          // 0=q, 1=k, 2=v (wave-uniform)
        int d = (ct & 3) * 16 + l15;
        if (region < 2) {
            unsigned short* dst = (region == 0) ? rq_p : rk_p;
            int ii = d >> 1;
            int ksq = d >> 5, quadq = (d >> 3) & 3, e = d & 7;
            #pragma unroll
            for (int mtl = 0; mtl < 2; ++mtl) {
                #pragma unroll
                for (int r = 0; r < 4; ++r) {
                    int row = row0 + (h * 2 + mtl) * 16 + quad * 4 + r;
                    int pos = row & (S_ - 1);
                    float cs = cs_t[pos * 32 + ii];
                    float sn = sn_t[pos * 32 + ii];
                    float val = acc[nt][mtl][r];
                    float partner = __shfl_xor(val, 1);   // pair col d^1 = lane^1
                    float res = (d & 1) ? fmaf(val, cs,  partner * sn)
                                        : fmaf(val, cs, -partner * sn);
                    int kt = pos >> 6, ntq = (pos >> 4) & 3, l15q = pos & 15;
                    size_t idx = ((((size_t)(b * 16 + kt) * 4 + ntq) * 2 + ksq) * 64
                                  + quadq * 16 + l15q) * 8 + e;
                    dst[idx] = f2bf(res);
                }
            }
        } else {
            int ntv = ct & 3;          // d = ntv*16 + l15
            #pragma unroll
            for (int mtl = 0; mtl < 2; ++mtl) {
                int sb2 = s_in_b + (h * 2 + mtl) * 16 + quad * 4;
                int kt = sb2 >> 6, ksv = (sb2 >> 5) & 1, quadv = (sb2 >> 3) & 3, e0 = sb2 & 7;
                ushort4 pk;
                pk.x = f2bf(acc[nt][mtl][0]);
                pk.y = f2bf(acc[nt][mtl][1]);
                pk.z = f2bf(acc[nt][mtl][2]);
                pk.w = f2bf(acc[nt][mtl][3]);
                size_t idx = ((((size_t)(b * 16 + kt) * 4 + ntv) * 2 + ksv) * 64
                              + quadv * 16 + l15) * 8 + e0;
                *(ushort4*)(vt_p + idx) = pk;
            }
        }
    }
}

// ---------------------------------------------------------------------------
// Flash attention — unchanged from rounds 3/4 (packed linear staging).
// ---------------------------------------------------------------------------
__global__ __launch_bounds__(256, 2) void attn_mfma_kernel(
    const unsigned short* __restrict__ rq_p, const unsigned short* __restrict__ rk_p,
    const unsigned short* __restrict__ vt_p, const unsigned int* __restrict__ flag,
    void* __restrict__ out)
{
    __shared__ __align__(16) unsigned short kv[2][32 * 512];   // 2 x 32 KB
    __shared__ unsigned short plds[4][16][72];                 // per-wave P buffer

    const bool isb = (*flag != 0);
    const int t    = threadIdx.x;
    const int lane = t & 63;
    const int wave = t >> 6;
    const int quad = lane >> 4;
    const int l15  = lane & 15;
    const int qt   = blockIdx.x;
    const int b    = blockIdx.y;
    const int q0   = qt * 64 + wave * 16;
    const float scale = 0.03608439182435161f;   // 768^-0.5

    // Q A-frags from packed tile (b, kt=qt, nt=wave)
    const unsigned short* qb = rq_p + ((size_t)((b * 16 + qt) * 4 + wave) * 2) * 512;
    short8 qf0 = *(const short8*)(qb + lane * 8);
    short8 qf1 = *(const short8*)(qb + 512 + lane * 8);

    // staging descriptors: this wave's 8 tiles, all linear
    const unsigned short* sbase[8];
    unsigned eo[8];
    int      slotv[8], tidv[8];
    #pragma unroll
    for (int i = 0; i < 8; ++i) {
        int tid = wave * 8 + i;
        tidv[i] = tid;
        int isV  = tid >> 4;             // 0=K, 1=V
        int rem  = tid & 15;
        int slot = rem >> 3;
        int wi   = rem & 7;
        int nt   = wi >> 1, ks = wi & 1;
        slotv[i] = slot;
        sbase[i] = isV ? vt_p : rk_p;
        eo[i]    = (unsigned)(((b * 64 + nt) * 2 + ks) * 512 + lane * 8);  // kt=0 base
    }

    float4v o[4];
    float m_[4], l_[4];
    #pragma unroll
    for (int nt = 0; nt < 4; ++nt)
        #pragma unroll
        for (int r = 0; r < 4; ++r) o[nt][r] = 0.f;
    #pragma unroll
    for (int r = 0; r < 4; ++r) { m_[r] = -1e30f; l_[r] = 0.f; }

    const int nIter = (qt + 2) >> 1;

    auto stage = [&](int it, int bsel) {
        int ta  = 2 * it;
        int tb  = min(ta + 1, qt);
        #pragma unroll
        for (int i = 0; i < 8; ++i) {
            int kt = slotv[i] ? tb : ta;
            gld_lds16(sbase[i] + eo[i] + (size_t)kt * 4096,   // kt stride = 4*2*512
                      &kv[bsel][(size_t)tidv[i] * 512]);
        }
    };

    stage(0, 0);
    int buf = 0;
    for (int i = 0; i < nIter; ++i) {
        __syncthreads();
        if (i + 1 < nIter) stage(i + 1, buf ^ 1);
        const unsigned short* kb = kv[buf];

        // ---- S = Q K^T for both slots ----
        float sc[2][4][4];
        #pragma unroll
        for (int slot = 0; slot < 2; ++slot) {
            #pragma unroll
            for (int nt = 0; nt < 4; ++nt) {
                float4v s;
                #pragma unroll
                for (int r = 0; r < 4; ++r) s[r] = 0.f;
                short8 kf0 = *(const short8*)(kb + (size_t)(slot * 8 + nt * 2 + 0) * 512 + lane * 8);
                short8 kf1 = *(const short8*)(kb + (size_t)(slot * 8 + nt * 2 + 1) * 512 + lane * 8);
                s = __builtin_amdgcn_mfma_f32_16x16x32_bf16(qf0, kf0, s, 0, 0, 0);
                s = __builtin_amdgcn_mfma_f32_16x16x32_bf16(qf1, kf1, s, 0, 0, 0);
                #pragma unroll
                for (int r = 0; r < 4; ++r) sc[slot][nt][r] = s[r] * scale;
            }
        }

        // ---- causal mask (wave-uniform trigger near diagonal) ----
        if (2 * i + 1 >= qt) {
            #pragma unroll
            for (int slot = 0; slot < 2; ++slot) {
                int ktl = 2 * i + slot;     // LOGICAL tile (dup tail -> all masked)
                #pragma unroll
                for (int nt = 0; nt < 4; ++nt) {
                    int kg = ktl * 64 + nt * 16 + l15;
                    #pragma unroll
                    for (int r = 0; r < 4; ++r) {
                        int qg = q0 + quad * 4 + r;
                        if (kg > qg) sc[slot][nt][r] = -1e30f;
                    }
                }
            }
        }

        // ---- online softmax over 128 keys (16-lane reduce) ----
        float mx[4];
        #pragma unroll
        for (int r = 0; r < 4; ++r) {
            float a0 = fmaxf(fmaxf(sc[0][0][r], sc[0][1][r]), fmaxf(sc[0][2][r], sc[0][3][r]));
            float a1 = fmaxf(fmaxf(sc[1][0][r], sc[1][1][r]), fmaxf(sc[1][2][r], sc[1][3][r]));
            mx[r] = fmaxf(a0, a1);
        }
        #pragma unroll
        for (int st = 1; st < 16; st <<= 1)
            #pragma unroll
            for (int r = 0; r < 4; ++r)
                mx[r] = fmaxf(mx[r], __shfl_xor(mx[r], st));

        float al[4];
        #pragma unroll
        for (int r = 0; r < 4; ++r) {
            float mn = fmaxf(m_[r], mx[r]);
            al[r] = __expf(m_[r] - mn);
            m_[r] = mn;
        }

        float sm[4] = {0.f, 0.f, 0.f, 0.f};
        #pragma unroll
        for (int slot = 0; slot < 2; ++slot)
            #pragma unroll
            for (int nt = 0; nt < 4; ++nt)
                #pragma unroll
                for (int r = 0; r < 4; ++r) {
                    float p = __expf(sc[slot][nt][r] - m_[r]);
                    sc[slot][nt][r] = p;
                    sm[r] += p;
                }
        #pragma unroll
        for (int st = 1; st < 16; st <<= 1)
            #pragma unroll
            for (int r = 0; r < 4; ++r)
                sm[r] += __shfl_xor(sm[r], st);
        #pragma unroll
        for (int r = 0; r < 4; ++r) l_[r] = l_[r] * al[r] + sm[r];

        #pragma unroll
        for (int nt = 0; nt < 4; ++nt)
            #pragma unroll
            for (int r = 0; r < 4; ++r) o[nt][r] *= al[r];

        // ---- per slot: P -> LDS -> A-frag; O += P V ----
        #pragma unroll
        for (int slot = 0; slot < 2; ++slot) {
            #pragma unroll
            for (int nt = 0; nt < 4; ++nt)
                #pragma unroll
                for (int r = 0; r < 4; ++r)
                    plds[wave][quad * 4 + r][nt * 16 + l15] = f2bf(sc[slot][nt][r]);
            short8 pf0 = *(const short8*)&plds[wave][l15][quad * 8];
            short8 pf1 = *(const short8*)&plds[wave][l15][32 + quad * 8];
            #pragma unroll
            for (int nt = 0; nt < 4; ++nt) {
                short8 vf0 = *(const short8*)(kb + (size_t)(16 + slot * 8 + nt * 2 + 0) * 512 + lane * 8);
                short8 vf1 = *(const short8*)(kb + (size_t)(16 + slot * 8 + nt * 2 + 1) * 512 + lane * 8);
                o[nt] = __builtin_amdgcn_mfma_f32_16x16x32_bf16(pf0, vf0, o[nt], 0, 0, 0);
                o[nt] = __builtin_amdgcn_mfma_f32_16x16x32_bf16(pf1, vf1, o[nt], 0, 0, 0);
            }
        }
        buf ^= 1;
    }

    // ---- epilogue: normalize, store per dtype ----
    float inv[4];
    #pragma unroll
    for (int r = 0; r < 4; ++r) inv[r] = 1.0f / l_[r];
    if (isb) {
        unsigned short* op = (unsigned short*)out;
        #pragma unroll
        for (int nt = 0; nt < 4; ++nt)
            #pragma unroll
            for (int r = 0; r < 4; ++r) {
                size_t row = (size_t)b * S_ + q0 + quad * 4 + r;
                op[row * HD_ + nt * 16 + l15] = f2bf(o[nt][r] * inv[r]);
            }
    } else {
        float* op = (float*)out;
        #pragma unroll
        for (int nt = 0; nt < 4; ++nt)
            #pragma unroll
            for (int r = 0; r < 4; ++r) {
                size_t row = (size_t)b * S_ + q0 + quad * 4 + r;
                op[row * HD_ + nt * 16 + l15] = o[nt][r] * inv[r];
            }
    }
}

// ---------------------------------------------------------------------------
extern "C" void kernel_launch(void* const* d_in, const int* in_sizes, int n_in,
                              void* d_out, int out_size, void* d_ws, size_t ws_size,
                              hipStream_t stream) {
    const void* x  = d_in[0];
    const void* Wq = d_in[1];
    const void* Wk = d_in[2];
    const void* Wv = d_in[3];

    // ws layout (~12.9 MB)
    unsigned int* flag = (unsigned int*)d_ws;
    float* cs_t = (float*)d_ws + 64;
    float* sn_t = cs_t + (size_t)S_ * 32;
    unsigned short* wp   = (unsigned short*)(sn_t + (size_t)S_ * 32);  // 288 tiles
    unsigned short* rq_p = wp + (size_t)288 * 512;
    unsigned short* rk_p = rq_p + (size_t)M_ * HD_;
    unsigned short* vt_p = rk_p + (size_t)M_ * HD_;

    hipLaunchKernelGGL(setup_kernel, dim3(201), dim3(256), 0, stream,
                       (const unsigned int*)x, Wq, Wk, Wv, flag, cs_t, sn_t, wp);
    hipLaunchKernelGGL(qkv_mfma_kernel, dim3(M_ / 64), dim3(512), 0, stream,
                       x, wp, flag, cs_t, sn_t, rq_p, rk_p, vt_p);
    hipLaunchKernelGGL(attn_mfma_kernel, dim3(S_ / 64, B_), dim3(256), 0, stream,
                       rq_p, rk_p, vt_p, flag, d_out);
}

// Round 6
// 190.579 us; speedup vs baseline: 1.0937x; 1.0220x over previous
//
#include <hip/hip_runtime.h>
#include <hip/hip_bf16.h>

#define B_  32
#define S_  1024
#define E_  768
#define HD_ 64
#define M_  (B_*S_)   // 32768 rows of x

typedef __attribute__((ext_vector_type(8))) short short8;   // 8 bf16 (4 VGPR)
typedef __attribute__((ext_vector_type(4))) float float4v;  // MFMA acc

// fp32 -> bf16 round-to-nearest-even
__device__ __forceinline__ unsigned short f2bf(float x) {
    union { float f; unsigned u; } c; c.f = x;
    unsigned r = (c.u + 0x7FFFu + ((c.u >> 16) & 1u)) >> 16;
    return (unsigned short)r;
}

// async global->LDS, 16B per lane; LDS dest = wave-uniform tile base.
__device__ __forceinline__ void gld_lds16(const void* g, void* l) {
    __builtin_amdgcn_global_load_lds(
        (const __attribute__((address_space(1))) unsigned int*)g,
        (__attribute__((address_space(3))) unsigned int*)l,
        16, 0, 0);
}

// ---------------------------------------------------------------------------
// Fused setup: RoPE tables (blocks 0..127), dtype sniffer -> flag (block 128),
// W pre-pack (blocks 129..200; inline per-block sniff avoids flag race).
// Wp[ct(12)][c(12)][ks(2)][lane(64)][8 bf16] fragment order (r3, verified).
// ---------------------------------------------------------------------------
__global__ __launch_bounds__(256) void setup_kernel(
    const unsigned int* __restrict__ xw,
    const void* __restrict__ Wq_, const void* __restrict__ Wk_,
    const void* __restrict__ Wv_,
    unsigned int* __restrict__ flag,
    float* __restrict__ cs_t, float* __restrict__ sn_t,
    unsigned short* __restrict__ wp)
{
    const int bx = blockIdx.x;
    if (bx < 128) {                     // RoPE tables
        int idx = bx * 256 + threadIdx.x;   // 0 .. 32767
        int pos = idx >> 5;
        int ii  = idx & 31;
        float theta = exp2f(-(float)ii * 0.8304820237218406f);  // log2(10000)/16
        float fr = (float)pos * theta;
        float sn, cs;
        sincosf(fr, &sn, &cs);
        cs_t[idx] = cs;
        sn_t[idx] = sn;
        return;
    }
    // blocks 128..200: sniff dtype (verified rounds 2-5 logic)
    __shared__ int cnt;
    if (threadIdx.x == 0) cnt = 0;
    __syncthreads();
    unsigned int w0 = xw[(size_t)threadIdx.x * 33331];
    unsigned int e0 = (w0 >> 8) & 0x7F;
    int hit = (e0 >= 0x3B && e0 <= 0x40) ? 1 : 0;
    atomicAdd(&cnt, hit);
    __syncthreads();
    const bool isb = (cnt > 128);
    if (bx == 128) {
        if (threadIdx.x == 0) *flag = isb ? 1u : 0u;
        return;
    }
    // wpack body (blocks 129..200 -> gid 0..18431)
    int gid  = (bx - 129) * 256 + threadIdx.x;
    int lane = gid & 63;
    int tIdx = gid >> 6;                          // 0..287
    int ct   = tIdx / 24;
    int rem  = tIdx - ct * 24;
    int c    = rem >> 1, ks = rem & 1;
    int quad = lane >> 4, l15 = lane & 15;
    const void* wsel = (ct < 4) ? Wq_ : (ct < 8 ? Wk_ : Wv_);
    int row = (ct & 3) * 16 + l15;
    int col = c * 64 + ks * 32 + quad * 8;
    uint4 w;
    if (isb) {
        w = *(const uint4*)((const unsigned short*)wsel + (size_t)row * E_ + col);
    } else {
        const float* f = (const float*)wsel + (size_t)row * E_ + col;
        float4 a = *(const float4*)f, bq = *(const float4*)(f + 4);
        w.x = f2bf(a.x)  | ((unsigned)f2bf(a.y)  << 16);
        w.y = f2bf(a.z)  | ((unsigned)f2bf(a.w)  << 16);
        w.z = f2bf(bq.x) | ((unsigned)f2bf(bq.y) << 16);
        w.w = f2bf(bq.z) | ((unsigned)f2bf(bq.w) << 16);
    }
    *(uint4*)(wp + (size_t)gid * 8) = w;
}

// ---------------------------------------------------------------------------
// QKV projection + RoPE — UNCHANGED from round 5 (B direct-to-reg, A via
// 1-gld_lds/wave/chunk ring-3, counted vmcnt(1)). qkv ~48us, proven.
// ---------------------------------------------------------------------------
__global__ __launch_bounds__(512, 4) void qkv_mfma_kernel(
    const void* __restrict__ x_, const unsigned short* __restrict__ wp,
    const unsigned int* __restrict__ flag,
    const float* __restrict__ cs_t, const float* __restrict__ sn_t,
    unsigned short* __restrict__ rq_p, unsigned short* __restrict__ rk_p,
    unsigned short* __restrict__ vt_p)
{
    __shared__ __align__(16) char alds[3][8192];   // A ring

    const bool isb = (*flag != 0);
    const int t    = threadIdx.x;
    const int lane = t & 63;
    const int wave = t >> 6;        // 0..7
    const int quad = lane >> 4;
    const int l15  = lane & 15;
    const int row0 = blockIdx.x * 64;
    const int h    = wave >> 2;     // row half: mt tiles {h*2, h*2+1}
    const int cw   = wave & 3;      // col group: ct = cw*3 + nt

    // A stage descriptor: 1 instr/wave/chunk; wave covers rows wave*8..+7.
    const unsigned aRow = (unsigned)(wave * 8 + (lane >> 3));
    const unsigned eoA  = aRow * 768u + (unsigned)(((lane & 7) ^ (lane >> 3)) * 8);

    // A fragment read byte-addrs within a slot
    unsigned aA[2][2];
    #pragma unroll
    for (int mtl = 0; mtl < 2; ++mtl) {
        unsigned rl = (unsigned)((h * 2 + mtl) * 16 + l15);
        #pragma unroll
        for (int ks = 0; ks < 2; ++ks)
            aA[mtl][ks] = rl * 128u + ((((unsigned)ks << 2) | (unsigned)quad) ^ (rl & 7u)) * 16u;
    }

    // B fragment bases (chunk stride = 1024 elems)
    const unsigned short* wbase[3][2];
    #pragma unroll
    for (int nt = 0; nt < 3; ++nt) {
        int ct = cw * 3 + nt;
        #pragma unroll
        for (int ks = 0; ks < 2; ++ks)
            wbase[nt][ks] = wp + ((size_t)(ct * 24 + ks)) * 512 + lane * 8;
    }

    float4v acc[3][2];
    #pragma unroll
    for (int nt = 0; nt < 3; ++nt)
        #pragma unroll
        for (int mtl = 0; mtl < 2; ++mtl)
            #pragma unroll
            for (int r = 0; r < 4; ++r) acc[nt][mtl][r] = 0.f;

    short8 breg[2][3][2];   // double-buffered B frags

    const unsigned short* xb16 = (const unsigned short*)x_ + (size_t)row0 * E_;
    const float*          xb32 = (const float*)x_ + (size_t)row0 * E_;

    #define LOADB(cc, sel)                                                       \
        {   int tc_ = (cc) < 11 ? (cc) : 11;                                     \
            _Pragma("unroll")                                                    \
            for (int nt_ = 0; nt_ < 3; ++nt_)                                    \
                _Pragma("unroll")                                                \
                for (int ks_ = 0; ks_ < 2; ++ks_)                                \
                    breg[sel][nt_][ks_] =                                        \
                        *(const short8*)(wbase[nt_][ks_] + tc_ * 1024);          \
        }

    #define COMPUTE(cc, sel)                                                     \
        {   const char* sb_ = alds[(cc) % 3];                                    \
            _Pragma("unroll")                                                    \
            for (int ks_ = 0; ks_ < 2; ++ks_) {                                  \
                short8 af0 = *(const short8*)(sb_ + aA[0][ks_]);                 \
                short8 af1 = *(const short8*)(sb_ + aA[1][ks_]);                 \
                _Pragma("unroll")                                                \
                for (int nt_ = 0; nt_ < 3; ++nt_) {                              \
                    acc[nt_][0] = __builtin_amdgcn_mfma_f32_16x16x32_bf16(       \
                        af0, breg[sel][nt_][ks_], acc[nt_][0], 0, 0, 0);         \
                    acc[nt_][1] = __builtin_amdgcn_mfma_f32_16x16x32_bf16(       \
                        af1, breg[sel][nt_][ks_], acc[nt_][1], 0, 0, 0);         \
                }                                                                \
            }                                                                    \
        }

    if (isb) {
        LOADB(0, 0);
        __builtin_amdgcn_sched_barrier(0);
        gld_lds16(xb16 + eoA,      alds[0] + wave * 1024);
        gld_lds16(xb16 + eoA + 64, alds[1] + wave * 1024);
        __builtin_amdgcn_sched_barrier(0);
        #pragma unroll
        for (int c = 0; c < 12; ++c) {
            asm volatile("s_waitcnt vmcnt(1)" ::: "memory");
            __builtin_amdgcn_s_barrier();
            LOADB(c + 1, (c + 1) & 1);
            __builtin_amdgcn_sched_barrier(0);
            {
                int tc = (c + 2) < 11 ? (c + 2) : 11;
                gld_lds16(xb16 + eoA + tc * 64, alds[(c + 2) % 3] + wave * 1024);
            }
            __builtin_amdgcn_sched_barrier(0);
            COMPUTE(c, c & 1);
        }
    } else {
        auto stageA_f = [&](int c) {
            const float* f = xb32 + eoA + c * 64;
            float4 a = *(const float4*)f, bq = *(const float4*)(f + 4);
            uint4 w;
            w.x = f2bf(a.x)  | ((unsigned)f2bf(a.y)  << 16);
            w.y = f2bf(a.z)  | ((unsigned)f2bf(a.w)  << 16);
            w.z = f2bf(bq.x) | ((unsigned)f2bf(bq.y) << 16);
            w.w = f2bf(bq.z) | ((unsigned)f2bf(bq.w) << 16);
            *(uint4*)(alds[c % 3] + wave * 1024 + (size_t)lane * 16) = w;
        };
        stageA_f(0); stageA_f(1);
        LOADB(0, 0);
        __syncthreads();
        #pragma unroll
        for (int c = 0; c < 12; ++c) {
            if (c + 2 < 12) stageA_f(c + 2);
            LOADB(c + 1, (c + 1) & 1);
            COMPUTE(c, c & 1);
            __syncthreads();
        }
    }
    #undef LOADB
    #undef COMPUTE

    // ---- Epilogue (unchanged r3/r4, verified): C col=l15, row=quad*4+r.
    const int b      = row0 >> 10;
    const int s_in_b = row0 & (S_ - 1);
    #pragma unroll
    for (int nt = 0; nt < 3; ++nt) {
        int ct = cw * 3 + nt;
        int region = ct >> 2;          // 0=q, 1=k, 2=v (wave-uniform)
        int d = (ct & 3) * 16 + l15;
        if (region < 2) {
            unsigned short* dst = (region == 0) ? rq_p : rk_p;
            int ii = d >> 1;
            int ksq = d >> 5, quadq = (d >> 3) & 3, e = d & 7;
            #pragma unroll
            for (int mtl = 0; mtl < 2; ++mtl) {
                #pragma unroll
                for (int r = 0; r < 4; ++r) {
                    int row = row0 + (h * 2 + mtl) * 16 + quad * 4 + r;
                    int pos = row & (S_ - 1);
                    float cs = cs_t[pos * 32 + ii];
                    float sn = sn_t[pos * 32 + ii];
                    float val = acc[nt][mtl][r];
                    float partner = __shfl_xor(val, 1);   // pair col d^1 = lane^1
                    float res = (d & 1) ? fmaf(val, cs,  partner * sn)
                                        : fmaf(val, cs, -partner * sn);
                    int kt = pos >> 6, ntq = (pos >> 4) & 3, l15q = pos & 15;
                    size_t idx = ((((size_t)(b * 16 + kt) * 4 + ntq) * 2 + ksq) * 64
                                  + quadq * 16 + l15q) * 8 + e;
                    dst[idx] = f2bf(res);
                }
            }
        } else {
            int ntv = ct & 3;          // d = ntv*16 + l15
            #pragma unroll
            for (int mtl = 0; mtl < 2; ++mtl) {
                int sb2 = s_in_b + (h * 2 + mtl) * 16 + quad * 4;
                int kt = sb2 >> 6, ksv = (sb2 >> 5) & 1, quadv = (sb2 >> 3) & 3, e0 = sb2 & 7;
                ushort4 pk;
                pk.x = f2bf(acc[nt][mtl][0]);
                pk.y = f2bf(acc[nt][mtl][1]);
                pk.z = f2bf(acc[nt][mtl][2]);
                pk.w = f2bf(acc[nt][mtl][3]);
                size_t idx = ((((size_t)(b * 16 + kt) * 4 + ntv) * 2 + ksv) * 64
                              + quadv * 16 + l15) * 8 + e0;
                *(ushort4*)(vt_p + idx) = pk;
            }
        }
    }
}

// ---------------------------------------------------------------------------
// Flash attention — ROUND-6 CHANGE: direct global->VGPR K/V fragments from
// the PACKED layouts (each frag load = coalesced 1KB/wave: lane*16B
// contiguous). Removes all 32 gld_lds/iter/block + BOTH barriers (plds is
// wave-local). LDS 74KB -> 9KB => occupancy VGPR-bound (~3 blocks/CU vs 2),
// smoothing causal load imbalance. V loads issued before softmax so HBM/L2
// latency hides under the VALU phase. r1's direct-load failure was the
// SCATTERED layout (16x64B/load) + launch_bounds(256,4) VGPR cap; both fixed.
// Grid (16, 32), block 256 (4 independent waves, 16 q-rows each).
// ---------------------------------------------------------------------------
__global__ __launch_bounds__(256, 2) void attn_mfma_kernel(
    const unsigned short* __restrict__ rq_p, const unsigned short* __restrict__ rk_p,
    const unsigned short* __restrict__ vt_p, const unsigned int* __restrict__ flag,
    void* __restrict__ out)
{
    __shared__ unsigned short plds[4][16][72];                 // per-wave P buffer

    const bool isb = (*flag != 0);
    const int t    = threadIdx.x;
    const int lane = t & 63;
    const int wave = t >> 6;
    const int quad = lane >> 4;
    const int l15  = lane & 15;
    const int qt   = blockIdx.x;
    const int b    = blockIdx.y;
    const int q0   = qt * 64 + wave * 16;
    const float scale = 0.03608439182435161f;   // 768^-0.5

    // Q A-frags from packed tile (b, kt=qt, nt=wave)
    const unsigned short* qb = rq_p + ((size_t)((b * 16 + qt) * 4 + wave) * 2) * 512;
    short8 qf0 = *(const short8*)(qb + lane * 8);
    short8 qf1 = *(const short8*)(qb + 512 + lane * 8);

    // packed tile base: tile (kt,nt,ks) at ((b*64 + kt*4 + nt)*2 + ks)*512 + lane*8
    const unsigned short* kb0 = rk_p + ((size_t)b * 128) * 512 + lane * 8;
    const unsigned short* vb0 = vt_p + ((size_t)b * 128) * 512 + lane * 8;

    float4v o[4];
    float m_[4], l_[4];
    #pragma unroll
    for (int nt = 0; nt < 4; ++nt)
        #pragma unroll
        for (int r = 0; r < 4; ++r) o[nt][r] = 0.f;
    #pragma unroll
    for (int r = 0; r < 4; ++r) { m_[r] = -1e30f; l_[r] = 0.f; }

    const int nIter = (qt + 2) >> 1;

    for (int i = 0; i < nIter; ++i) {
        const int ta = 2 * i;
        const int tb = min(ta + 1, qt);     // dup tail fully masked via logical kg
        const int ktv[2] = { ta, tb };

        // ---- K frags -> regs (coalesced 1KB/wave each) ----
        short8 kf[2][4][2];
        #pragma unroll
        for (int slot = 0; slot < 2; ++slot)
            #pragma unroll
            for (int nt = 0; nt < 4; ++nt)
                #pragma unroll
                for (int ks = 0; ks < 2; ++ks)
                    kf[slot][nt][ks] = *(const short8*)(
                        kb0 + (size_t)(ktv[slot] * 8 + nt * 2 + ks) * 512);

        // ---- S = Q K^T for both slots ----
        float sc[2][4][4];
        #pragma unroll
        for (int slot = 0; slot < 2; ++slot) {
            #pragma unroll
            for (int nt = 0; nt < 4; ++nt) {
                float4v s;
                #pragma unroll
                for (int r = 0; r < 4; ++r) s[r] = 0.f;
                s = __builtin_amdgcn_mfma_f32_16x16x32_bf16(qf0, kf[slot][nt][0], s, 0, 0, 0);
                s = __builtin_amdgcn_mfma_f32_16x16x32_bf16(qf1, kf[slot][nt][1], s, 0, 0, 0);
                #pragma unroll
                for (int r = 0; r < 4; ++r) sc[slot][nt][r] = s[r] * scale;
            }
        }

        // ---- V frags -> regs NOW (latency hides under softmax VALU) ----
        short8 vf[2][4][2];
        #pragma unroll
        for (int slot = 0; slot < 2; ++slot)
            #pragma unroll
            for (int nt = 0; nt < 4; ++nt)
                #pragma unroll
                for (int ks = 0; ks < 2; ++ks)
                    vf[slot][nt][ks] = *(const short8*)(
                        vb0 + (size_t)(ktv[slot] * 8 + nt * 2 + ks) * 512);

        // ---- causal mask (wave-uniform trigger near diagonal) ----
        if (2 * i + 1 >= qt) {
            #pragma unroll
            for (int slot = 0; slot < 2; ++slot) {
                int ktl = 2 * i + slot;     // LOGICAL tile (dup tail -> all masked)
                #pragma unroll
                for (int nt = 0; nt < 4; ++nt) {
                    int kg = ktl * 64 + nt * 16 + l15;
                    #pragma unroll
                    for (int r = 0; r < 4; ++r) {
                        int qg = q0 + quad * 4 + r;
                        if (kg > qg) sc[slot][nt][r] = -1e30f;
                    }
                }
            }
        }

        // ---- online softmax over 128 keys (16-lane reduce) ----
        float mx[4];
        #pragma unroll
        for (int r = 0; r < 4; ++r) {
            float a0 = fmaxf(fmaxf(sc[0][0][r], sc[0][1][r]), fmaxf(sc[0][2][r], sc[0][3][r]));
            float a1 = fmaxf(fmaxf(sc[1][0][r], sc[1][1][r]), fmaxf(sc[1][2][r], sc[1][3][r]));
            mx[r] = fmaxf(a0, a1);
        }
        #pragma unroll
        for (int st = 1; st < 16; st <<= 1)
            #pragma unroll
            for (int r = 0; r < 4; ++r)
                mx[r] = fmaxf(mx[r], __shfl_xor(mx[r], st));

        float al[4];
        #pragma unroll
        for (int r = 0; r < 4; ++r) {
            float mn = fmaxf(m_[r], mx[r]);
            al[r] = __expf(m_[r] - mn);
            m_[r] = mn;
        }

        float sm[4] = {0.f, 0.f, 0.f, 0.f};
        #pragma unroll
        for (int slot = 0; slot < 2; ++slot)
            #pragma unroll
            for (int nt = 0; nt < 4; ++nt)
                #pragma unroll
                for (int r = 0; r < 4; ++r) {
                    float p = __expf(sc[slot][nt][r] - m_[r]);
                    sc[slot][nt][r] = p;
                    sm[r] += p;
                }
        #pragma unroll
        for (int st = 1; st < 16; st <<= 1)
            #pragma unroll
            for (int r = 0; r < 4; ++r)
                sm[r] += __shfl_xor(sm[r], st);
        #pragma unroll
        for (int r = 0; r < 4; ++r) l_[r] = l_[r] * al[r] + sm[r];

        #pragma unroll
        for (int nt = 0; nt < 4; ++nt)
            #pragma unroll
            for (int r = 0; r < 4; ++r) o[nt][r] *= al[r];

        // ---- per slot: P -> plds (wave-local) -> A-frag; O += P V ----
        #pragma unroll
        for (int slot = 0; slot < 2; ++slot) {
            #pragma unroll
            for (int nt = 0; nt < 4; ++nt)
                #pragma unroll
                for (int r = 0; r < 4; ++r)
                    plds[wave][quad * 4 + r][nt * 16 + l15] = f2bf(sc[slot][nt][r]);
            short8 pf0 = *(const short8*)&plds[wave][l15][quad * 8];
            short8 pf1 = *(const short8*)&plds[wave][l15][32 + quad * 8];
            #pragma unroll
            for (int nt = 0; nt < 4; ++nt) {
                o[nt] = __builtin_amdgcn_mfma_f32_16x16x32_bf16(pf0, vf[slot][nt][0], o[nt], 0, 0, 0);
                o[nt] = __builtin_amdgcn_mfma_f32_16x16x32_bf16(pf1, vf[slot][nt][1], o[nt], 0, 0, 0);
            }
        }
    }

    // ---- epilogue: normalize, store per dtype ----
    float inv[4];
    #pragma unroll
    for (int r = 0; r < 4; ++r) inv[r] = 1.0f / l_[r];
    if (isb) {
        unsigned short* op = (unsigned short*)out;
        #pragma unroll
        for (int nt = 0; nt < 4; ++nt)
            #pragma unroll
            for (int r = 0; r < 4; ++r) {
                size_t row = (size_t)b * S_ + q0 + quad * 4 + r;
                op[row * HD_ + nt * 16 + l15] = f2bf(o[nt][r] * inv[r]);
            }
    } else {
        float* op = (float*)out;
        #pragma unroll
        for (int nt = 0; nt < 4; ++nt)
            #pragma unroll
            for (int r = 0; r < 4; ++r) {
                size_t row = (size_t)b * S_ + q0 + quad * 4 + r;
                op[row * HD_ + nt * 16 + l15] = o[nt][r] * inv[r];
            }
    }
}

// ---------------------------------------------------------------------------
extern "C" void kernel_launch(void* const* d_in, const int* in_sizes, int n_in,
                              void* d_out, int out_size, void* d_ws, size_t ws_size,
                              hipStream_t stream) {
    const void* x  = d_in[0];
    const void* Wq = d_in[1];
    const void* Wk = d_in[2];
    const void* Wv = d_in[3];

    // ws layout (~12.9 MB)
    unsigned int* flag = (unsigned int*)d_ws;
    float* cs_t = (float*)d_ws + 64;
    float* sn_t = cs_t + (size_t)S_ * 32;
    unsigned short* wp   = (unsigned short*)(sn_t + (size_t)S_ * 32);  // 288 tiles
    unsigned short* rq_p = wp + (size_t)288 * 512;
    unsigned short* rk_p = rq_p + (size_t)M_ * HD_;
    unsigned short* vt_p = rk_p + (size_t)M_ * HD_;

    hipLaunchKernelGGL(setup_kernel, dim3(201), dim3(256), 0, stream,
                       (const unsigned int*)x, Wq, Wk, Wv, flag, cs_t, sn_t, wp);
    hipLaunchKernelGGL(qkv_mfma_kernel, dim3(M_ / 64), dim3(512), 0, stream,
                       x, wp, flag, cs_t, sn_t, rq_p, rk_p, vt_p);
    hipLaunchKernelGGL(attn_mfma_kernel, dim3(S_ / 64, B_), dim3(256), 0, stream,
                       rq_p, rk_p, vt_p, flag, d_out);
}